// Round 7
// baseline (142.481 us; speedup 1.0000x reference)
//
#include <hip/hip_runtime.h>

#define NPTS  4096
#define BQ    16
#define NT    256
#define OPT   8                 // outer points per thread (VALU path)
#define SEG   8                 // inner-dimension segments
#define SEGN  (NPTS / SEG)      // 512
#define OTILE (NT * OPT)        // 2048
#define ILV   4
#define WC    8                 // probe2: col-tiles per wave
#define P2N   128               // probe2: inner points
#define P2T   (P2N / 16)        // 8 tiles

typedef short bhalf8  __attribute__((ext_vector_type(8)));
typedef float floatx4 __attribute__((ext_vector_type(4)));

__device__ __forceinline__ short f2bf(float f) {
    unsigned u = __float_as_uint(f);
    unsigned r = (u + 0x7FFFu + ((u >> 16) & 1u)) >> 16;   // RNE
    return (short)r;
}
__device__ __forceinline__ float bf2f(short s) {
    return __uint_as_float(((unsigned)(unsigned short)s) << 16);
}
__device__ __forceinline__ float min3f(float a, float b, float c) {
    float d;
    asm("v_min3_f32 %0, %1, %2, %3" : "=v"(d) : "v"(a), "v"(b), "v"(c));
    return d;
}

// ---------- Probe 1: raw MFMA layout/semantics check ----------
// A[r][k]: k0=r, k1=1, else 0.  B[k][c]: k0=16, k1=c, else 0.
// True matmul => D[r][c] = 16r + c (exact integers in bf16/f32).
// Checks assumed maps: A row=lane&15 kgrp=lane>>4; B col=lane&15;
// D col=lane&15, row=(lane>>4)*4+reg (verified m89).
__global__ void probe1_kernel(float* __restrict__ diag)
{
    const int lane = (int)threadIdx.x;   // 64 threads
    bhalf8 aF = {0,0,0,0,0,0,0,0};
    bhalf8 bF = {0,0,0,0,0,0,0,0};
    if (lane < 16) {
        aF[0] = f2bf((float)lane); aF[1] = f2bf(1.0f);
        bF[0] = f2bf(16.0f);       bF[1] = f2bf((float)lane);
    }
    const floatx4 z = {0.0f, 0.0f, 0.0f, 0.0f};
    const floatx4 d = __builtin_amdgcn_mfma_f32_16x16x32_bf16(aF, bF, z, 0, 0, 0);

    int okn = 1, oks = 1;
    float v2 = 0.0f;
#pragma unroll
    for (int i = 0; i < 4; ++i) {
        const float v  = d[i];
        const float vr = rintf(v);
        const int   vi = (int)vr;
        const int valid = (fabsf(v - vr) < 0.25f) && (vi >= 0) && (vi < 256);
        const int row = (lane >> 4) * 4 + i;
        const int col = lane & 15;
        okn &= (valid && vi == 16 * row + col) ? 1 : 0;
        oks &= (valid && vi == 16 * col + row) ? 1 : 0;
        if (i == 2) v2 = v;
    }
    const int alln = __all(okn);
    const int alls = __all(oks);
    const float sample = __shfl(v2, 5, 64);   // lane5,reg2: expect 16*6+5=101
    if (lane == 0) {
        float dg = 0.0f;
        if (!alln) dg = alls ? 2000.0f
                             : 1000.0f + fminf(fmaxf(sample, -400.0f), 400.0f);
        diag[0] = dg;
    }
}

// ---------- Probe 2: replicate R6 pass-1 structure vs in-kernel VALU ref ----------
__global__ __launch_bounds__(256)
void probe2_kernel(const float* __restrict__ preds,
                   const float* __restrict__ gts,
                   float* __restrict__ diag)
{
    __shared__ bhalf8 s_frag[P2T * 32];
    __shared__ int    s_bad[256];

    const float* ob = preds;   // batch 0, dir 0: outer = preds
    const float* ib = gts;     // inner = gts
    const int tid = (int)threadIdx.x;

    // stage A fragments exactly as R6
    for (int p = tid; p < P2N; p += 256) {
        const float x0 = ib[p * 3 + 0], x1 = ib[p * 3 + 1], x2 = ib[p * 3 + 2];
        const float a0 = -2.0f * x0, a1 = -2.0f * x1, a2 = -2.0f * x2;
        const short h0 = f2bf(a0), h1 = f2bf(a1), h2 = f2bf(a2);
        const short l0 = f2bf(a0 - bf2f(h0));
        const short l1 = f2bf(a1 - bf2f(h1));
        const short l2 = f2bf(a2 - bf2f(h2));
        const float xx = x0 * x0 + x1 * x1 + x2 * x2;
        const short xh = f2bf(xx);
        const short xl = f2bf(xx - bf2f(xh));
        bhalf8 e0, e1;
        e0[0] = h0; e0[1] = h1; e0[2] = h2; e0[3] = l0;
        e0[4] = l1; e0[5] = l2; e0[6] = xh; e0[7] = xl;
        e1[0] = h0; e1[1] = h1; e1[2] = h2; e1[3] = l0;
        e1[4] = l1; e1[5] = l2; e1[6] = 0;  e1[7] = 0;
        const int t = p >> 4, r = p & 15;
        s_frag[t * 32 + r]      = e0;
        s_frag[t * 32 + 16 + r] = e1;
    }

    const int wv   = tid >> 6;
    const int lane = tid & 63;
    const int g    = lane >> 4;
    const int colbase = wv * (WC * 16);

    const bhalf8 z8 = {0, 0, 0, 0, 0, 0, 0, 0};

    bhalf8 bfrag[WC];
    float  ysp0[WC], ysp1[WC], ysp2[WC];
#pragma unroll
    for (int ct = 0; ct < WC; ++ct) {
        const int col = colbase + ct * 16 + (lane & 15);
        const float y0 = ob[col * 3 + 0], y1 = ob[col * 3 + 1], y2 = ob[col * 3 + 2];
        const short h0 = f2bf(y0), h1 = f2bf(y1), h2 = f2bf(y2);
        const short q0 = f2bf(y0 - bf2f(h0));
        const short q1 = f2bf(y1 - bf2f(h1));
        const short q2 = f2bf(y2 - bf2f(h2));
        ysp0[ct] = bf2f(h0) + bf2f(q0);   // effective y the MFMA multiplies
        ysp1[ct] = bf2f(h1) + bf2f(q1);
        ysp2[ct] = bf2f(h2) + bf2f(q2);
        bhalf8 f = z8;
        if (g == 0) {
            f[0] = h0; f[1] = h1; f[2] = h2; f[3] = h0; f[4] = h1; f[5] = h2;
            f[6] = (short)0x3F80; f[7] = (short)0x3F80;
        } else if (g == 1) {
            f[0] = q0; f[1] = q1; f[2] = q2; f[3] = q0; f[4] = q1; f[5] = q2;
        }
        bfrag[ct] = f;
    }
    __syncthreads();

    float accm[WC];
#pragma unroll
    for (int ct = 0; ct < WC; ++ct) accm[ct] = 3.0e38f;

    const floatx4 zacc = {0.0f, 0.0f, 0.0f, 0.0f};
#pragma unroll 2
    for (int t = 0; t < P2T; ++t) {
        bhalf8 a = z8;
        if (lane < 32) a = s_frag[t * 32 + lane];
#pragma unroll
        for (int ct = 0; ct < WC; ++ct) {
            const floatx4 c = __builtin_amdgcn_mfma_f32_16x16x32_bf16(a, bfrag[ct], zacc, 0, 0, 0);
            accm[ct] = min3f(accm[ct], min3f(c[0], c[1], c[2]), c[3]);
        }
    }

    int bad = 0;
#pragma unroll
    for (int ct = 0; ct < WC; ++ct) {
        float v = accm[ct];
        v = fminf(v, __shfl_xor(v, 16, 64));
        v = fminf(v, __shfl_xor(v, 32, 64));
        // VALU reference over the SAME split operands
        float rmin = 3.0e38f;
#pragma unroll 1
        for (int p = 0; p < P2N; ++p) {
            const bhalf8 e = s_frag[(p >> 4) * 32 + (p & 15)];
            const float a0 = bf2f(e[0]) + bf2f(e[3]);
            const float a1 = bf2f(e[1]) + bf2f(e[4]);
            const float a2 = bf2f(e[2]) + bf2f(e[5]);
            const float xx = bf2f(e[6]) + bf2f(e[7]);
            rmin = fminf(rmin, xx + a0 * ysp0[ct] + a1 * ysp1[ct] + a2 * ysp2[ct]);
        }
        if (lane < 16 && fabsf(v - rmin) > 5.0e-3f) bad = 1;
    }
    s_bad[tid] = bad;
    __syncthreads();
    for (int s = 128; s > 0; s >>= 1) {
        if (tid < s) s_bad[tid] += s_bad[tid + s];
        __syncthreads();
    }
    if (tid == 0) diag[1] = (s_bad[0] > 0) ? 10000.0f : 0.0f;
}

// ---------- Verified R4 VALU pipeline ----------
__global__ __launch_bounds__(NT, 2)
void chamfer_part_kernel(const float* __restrict__ preds,
                         const float* __restrict__ gts,
                         float* __restrict__ partial)
{
    __shared__ float4 s_pts[SEGN];   // 8 KB

    const int tile = blockIdx.x;
    const int seg  = blockIdx.y;
    const int bd   = blockIdx.z;
    const int dir  = bd >> 4;
    const int b    = bd & 15;

    const float* outer = (dir == 0) ? preds : gts;
    const float* inner = (dir == 0) ? gts   : preds;
    const float* ob = outer + (size_t)b * NPTS * 3;
    const float* ib = inner + (size_t)b * NPTS * 3 + (size_t)seg * SEGN * 3;

    for (int idx = (int)threadIdx.x; idx < SEGN; idx += NT) {
        const float x0 = ib[idx * 3 + 0];
        const float x1 = ib[idx * 3 + 1];
        const float x2 = ib[idx * 3 + 2];
        s_pts[idx] = make_float4(x0, x1, x2, x0 * x0 + x1 * x1 + x2 * x2);
    }

    float c0[OPT], c1[OPT], c2[OPT], yy[OPT];
#pragma unroll
    for (int u = 0; u < OPT; ++u) {
        const int o = tile * OTILE + u * NT + (int)threadIdx.x;
        const float y0 = ob[o * 3 + 0];
        const float y1 = ob[o * 3 + 1];
        const float y2 = ob[o * 3 + 2];
        yy[u] = y0 * y0 + y1 * y1 + y2 * y2;
        c0[u] = -2.0f * y0; c1[u] = -2.0f * y1; c2[u] = -2.0f * y2;
    }
    __syncthreads();

    float m[OPT];
#pragma unroll
    for (int u = 0; u < OPT; ++u) m[u] = 3.0e38f;

#pragma unroll 1
    for (int i = 0; i < SEGN; i += ILV) {
        float4 p[ILV];
#pragma unroll
        for (int k = 0; k < ILV; ++k) p[k] = s_pts[i + k];
#pragma unroll
        for (int u = 0; u < OPT; ++u) {
            const float t0 = fmaf(c0[u], p[0].x, fmaf(c1[u], p[0].y, fmaf(c2[u], p[0].z, p[0].w)));
            const float t1 = fmaf(c0[u], p[1].x, fmaf(c1[u], p[1].y, fmaf(c2[u], p[1].z, p[1].w)));
            m[u] = fminf(fminf(m[u], t0), t1);
            const float t2 = fmaf(c0[u], p[2].x, fmaf(c1[u], p[2].y, fmaf(c2[u], p[2].z, p[2].w)));
            const float t3 = fmaf(c0[u], p[3].x, fmaf(c1[u], p[3].y, fmaf(c2[u], p[3].z, p[3].w)));
            m[u] = fminf(fminf(m[u], t2), t3);
        }
    }

#pragma unroll
    for (int u = 0; u < OPT; ++u) {
        const int o = tile * OTILE + u * NT + (int)threadIdx.x;
        partial[((size_t)bd * NPTS + o) * SEG + seg] = m[u] + yy[u];
    }
}

__global__ void chamfer_comb_kernel(const float* __restrict__ partial,
                                    float* __restrict__ blockpart)
{
    __shared__ float s_red[NT];
    float sum = 0.0f;
#pragma unroll
    for (int i = 0; i < 4; ++i) {
        const int slot = (int)blockIdx.x * 1024 + i * NT + (int)threadIdx.x;
        const float4 pa = ((const float4*)partial)[slot * 2 + 0];
        const float4 pb = ((const float4*)partial)[slot * 2 + 1];
        const float mn = fminf(fminf(fminf(pa.x, pa.y), fminf(pa.z, pa.w)),
                               fminf(fminf(pb.x, pb.y), fminf(pb.z, pb.w)));
        sum += mn;
    }
    s_red[threadIdx.x] = sum;
    __syncthreads();
#pragma unroll
    for (int s = NT / 2; s > 0; s >>= 1) {
        if ((int)threadIdx.x < s) s_red[threadIdx.x] += s_red[threadIdx.x + s];
        __syncthreads();
    }
    if (threadIdx.x == 0) blockpart[blockIdx.x] = s_red[0];
}

__global__ void chamfer_final_kernel(const float* __restrict__ blockpart,
                                     const float* __restrict__ diag,
                                     float* __restrict__ out)
{
    __shared__ float s_red[128];
    s_red[threadIdx.x] = blockpart[threadIdx.x];
    __syncthreads();
#pragma unroll
    for (int s = 64; s > 0; s >>= 1) {
        if ((int)threadIdx.x < s) s_red[threadIdx.x] += s_red[threadIdx.x + s];
        __syncthreads();
    }
    if (threadIdx.x == 0)
        out[0] = s_red[0] * (1.0f / (float)(BQ * NPTS)) + diag[0] + diag[1];
}

extern "C" void kernel_launch(void* const* d_in, const int* in_sizes, int n_in,
                              void* d_out, int out_size, void* d_ws, size_t ws_size,
                              hipStream_t stream)
{
    const float* preds = (const float*)d_in[0];
    const float* gts   = (const float*)d_in[1];
    float* out       = (float*)d_out;
    float* partial   = (float*)d_ws;                          // 4 MB
    float* blockpart = partial + (size_t)2 * BQ * NPTS * SEG; // +128 floats
    float* diag      = blockpart + 128;                       // +2 floats

    probe1_kernel<<<1, 64, 0, stream>>>(diag);
    probe2_kernel<<<1, 256, 0, stream>>>(preds, gts, diag);

    dim3 grid1(NPTS / OTILE, SEG, 2 * BQ);   // (2, 8, 32) = 512 blocks
    chamfer_part_kernel<<<grid1, NT, 0, stream>>>(preds, gts, partial);
    chamfer_comb_kernel<<<128, NT, 0, stream>>>(partial, blockpart);
    chamfer_final_kernel<<<1, 128, 0, stream>>>(blockpart, diag, out);
}

// Round 8
// 63.585 us; speedup vs baseline: 2.2408x; 2.2408x over previous
//
#include <hip/hip_runtime.h>

#define NPTS  4096
#define BQ    16
#define NT    256
#define SEG   4
#define SEGN  (NPTS / SEG)       // 1024 inner points per segment
#define NTILE (SEGN / 16)        // 64 inner tiles (16 points each)
#define WC    8                  // column-tiles (16 cols each) per wave
#define WCOLS (WC * 16)          // 128 cols per wave
#define BCOLS (4 * WCOLS)        // 512 cols per block (4 waves)

typedef short bhalf8  __attribute__((ext_vector_type(8)));   // 8 bf16 (4 VGPRs)
typedef float floatx4 __attribute__((ext_vector_type(4)));   // 16x16 MFMA acc

__device__ __forceinline__ short f2bf(float f) {
    unsigned u = __float_as_uint(f);
    unsigned r = (u + 0x7FFFu + ((u >> 16) & 1u)) >> 16;   // RNE
    return (short)r;
}
__device__ __forceinline__ float bf2f(short s) {
    return __uint_as_float(((unsigned)(unsigned short)s) << 16);
}

// zero the diagnostic slots each launch (determinism across graph replays)
__global__ void init_diag_kernel(int* __restrict__ idiag)
{
    if (threadIdx.x < 2) idiag[threadIdx.x] = 0;
}

// Pass 1 (MFMA): R6 structure verbatim EXCEPT the MFMA-consuming min is pure
// fminf (no inline asm reading MFMA results -> backend handles RAW hazards).
// grid (8, 4, 32) = 1024 blocks, 4/CU.
__global__ __launch_bounds__(NT, 4)
void chamfer_mfma_kernel(const float* __restrict__ preds,
                         const float* __restrict__ gts,
                         float* __restrict__ partial)
{
    __shared__ bhalf8 s_frag[NTILE * 32];   // 32 KB

    const int cb  = blockIdx.x;   // 0..7
    const int seg = blockIdx.y;   // 0..3
    const int bd  = blockIdx.z;   // 0..31
    const int dir = bd >> 4;
    const int b   = bd & 15;

    const float* outer = (dir == 0) ? preds : gts;
    const float* inner = (dir == 0) ? gts   : preds;
    const float* ob = outer + (size_t)b * NPTS * 3;
    const float* ib = inner + (size_t)b * NPTS * 3 + (size_t)seg * SEGN * 3;

    // ---- stage A fragments (inner points) ----
    for (int p = (int)threadIdx.x; p < SEGN; p += NT) {
        const float x0 = ib[p * 3 + 0], x1 = ib[p * 3 + 1], x2 = ib[p * 3 + 2];
        const float a0 = -2.0f * x0, a1 = -2.0f * x1, a2 = -2.0f * x2;
        const short h0 = f2bf(a0), h1 = f2bf(a1), h2 = f2bf(a2);
        const short l0 = f2bf(a0 - bf2f(h0));
        const short l1 = f2bf(a1 - bf2f(h1));
        const short l2 = f2bf(a2 - bf2f(h2));
        const float xx = x0 * x0 + x1 * x1 + x2 * x2;
        const short xh = f2bf(xx);
        const short xl = f2bf(xx - bf2f(xh));
        bhalf8 e0, e1;
        e0[0] = h0; e0[1] = h1; e0[2] = h2; e0[3] = l0;
        e0[4] = l1; e0[5] = l2; e0[6] = xh; e0[7] = xl;
        e1[0] = h0; e1[1] = h1; e1[2] = h2; e1[3] = l0;
        e1[4] = l1; e1[5] = l2; e1[6] = 0;  e1[7] = 0;
        const int t = p >> 4, r = p & 15;
        s_frag[t * 32 + r]      = e0;   // k-group 0 rows (lanes 0-15)
        s_frag[t * 32 + 16 + r] = e1;   // k-group 1 rows (lanes 16-31)
    }

    const int wv   = (int)threadIdx.x >> 6;
    const int lane = (int)threadIdx.x & 63;
    const int g    = lane >> 4;
    const int colbase = cb * BCOLS + wv * WCOLS;

    const bhalf8 z8 = {0, 0, 0, 0, 0, 0, 0, 0};

    bhalf8 bfrag[WC];
    float  yy[WC];
#pragma unroll
    for (int ct = 0; ct < WC; ++ct) {
        const int col = colbase + ct * 16 + (lane & 15);
        const float y0 = ob[col * 3 + 0], y1 = ob[col * 3 + 1], y2 = ob[col * 3 + 2];
        yy[ct] = y0 * y0 + y1 * y1 + y2 * y2;
        bhalf8 f = z8;
        if (g == 0) {          // k 0-7: [yhi(3), yhi(3), 1, 1]
            const short h0 = f2bf(y0), h1 = f2bf(y1), h2 = f2bf(y2);
            f[0] = h0; f[1] = h1; f[2] = h2; f[3] = h0; f[4] = h1; f[5] = h2;
            f[6] = (short)0x3F80; f[7] = (short)0x3F80;   // bf16 1.0
        } else if (g == 1) {   // k 8-15: [ylo(3), ylo(3), 0, 0]
            const short h0 = f2bf(y0), h1 = f2bf(y1), h2 = f2bf(y2);
            const short q0 = f2bf(y0 - bf2f(h0));
            const short q1 = f2bf(y1 - bf2f(h1));
            const short q2 = f2bf(y2 - bf2f(h2));
            f[0] = q0; f[1] = q1; f[2] = q2; f[3] = q0; f[4] = q1; f[5] = q2;
        }
        bfrag[ct] = f;
    }
    __syncthreads();

    float accm[WC];
#pragma unroll
    for (int ct = 0; ct < WC; ++ct) accm[ct] = 3.0e38f;

    const floatx4 zacc = {0.0f, 0.0f, 0.0f, 0.0f};

#pragma unroll 2
    for (int t = 0; t < NTILE; ++t) {
        bhalf8 a = z8;
        if (lane < 32) a = s_frag[t * 32 + lane];
#pragma unroll
        for (int ct = 0; ct < WC; ++ct) {
            const floatx4 c = __builtin_amdgcn_mfma_f32_16x16x32_bf16(a, bfrag[ct], zacc, 0, 0, 0);
            // pure fminf chain (compiler may fuse v_min3; backend owns MFMA hazards)
            accm[ct] = fminf(fminf(fminf(fminf(c[0], c[1]), c[2]), c[3]), accm[ct]);
        }
    }

#pragma unroll
    for (int ct = 0; ct < WC; ++ct) {
        float v = accm[ct];
        v = fminf(v, __shfl_xor(v, 16, 64));
        v = fminf(v, __shfl_xor(v, 32, 64));
        const float m = v + yy[ct];
        if (lane < 16) {
            const int col = colbase + ct * 16 + lane;
            partial[((size_t)bd * NPTS + col) * SEG + seg] = m;
        }
    }
}

// Sampled VALU verifier: bd in {0,17}, all cols, all segs (1/16 of entries).
// Each thread: one outer col vs full 1024-pt segment; compare vs partial.
// grid (16, 4, 2), block 256.
__global__ __launch_bounds__(NT)
void verify_kernel(const float* __restrict__ preds,
                   const float* __restrict__ gts,
                   const float* __restrict__ partial,
                   int* __restrict__ idiag)
{
    __shared__ float4 s_pts[SEGN];   // 16 KB
    __shared__ int s_cnt[NT];
    __shared__ int s_bits[NT];

    const int tile = blockIdx.x;                 // 0..15
    const int seg  = blockIdx.y;                 // 0..3
    const int bd   = (blockIdx.z == 0) ? 0 : 17;
    const int dir  = bd >> 4;
    const int b    = bd & 15;

    const float* outer = (dir == 0) ? preds : gts;
    const float* inner = (dir == 0) ? gts   : preds;
    const float* ob = outer + (size_t)b * NPTS * 3;
    const float* ib = inner + (size_t)b * NPTS * 3 + (size_t)seg * SEGN * 3;

    for (int idx = (int)threadIdx.x; idx < SEGN; idx += NT) {
        const float x0 = ib[idx * 3 + 0];
        const float x1 = ib[idx * 3 + 1];
        const float x2 = ib[idx * 3 + 2];
        s_pts[idx] = make_float4(x0, x1, x2, x0 * x0 + x1 * x1 + x2 * x2);
    }

    const int o = tile * NT + (int)threadIdx.x;
    const float y0 = ob[o * 3 + 0];
    const float y1 = ob[o * 3 + 1];
    const float y2 = ob[o * 3 + 2];
    const float yy = y0 * y0 + y1 * y1 + y2 * y2;
    const float c0 = -2.0f * y0, c1 = -2.0f * y1, c2 = -2.0f * y2;
    __syncthreads();

    float m0 = 3.0e38f, m1 = 3.0e38f, m2 = 3.0e38f, m3 = 3.0e38f;
#pragma unroll 1
    for (int i = 0; i < SEGN; i += 4) {
        const float4 pa = s_pts[i + 0];
        const float4 pb = s_pts[i + 1];
        const float4 pc = s_pts[i + 2];
        const float4 pd = s_pts[i + 3];
        m0 = fminf(m0, fmaf(c0, pa.x, fmaf(c1, pa.y, fmaf(c2, pa.z, pa.w))));
        m1 = fminf(m1, fmaf(c0, pb.x, fmaf(c1, pb.y, fmaf(c2, pb.z, pb.w))));
        m2 = fminf(m2, fmaf(c0, pc.x, fmaf(c1, pc.y, fmaf(c2, pc.z, pc.w))));
        m3 = fminf(m3, fmaf(c0, pd.x, fmaf(c1, pd.y, fmaf(c2, pd.z, pd.w))));
    }
    const float mv = fminf(fminf(m0, m1), fminf(m2, m3)) + yy;

    const float p2 = partial[((size_t)bd * NPTS + o) * SEG + seg];
    const int bad = (fabsf(p2 - mv) > 4.0e-3f + 2.0e-3f * fabsf(mv)) ? 1 : 0;
    int bits = 0;
    if (bad) {
        const int cb = o >> 9;
        bits = ((cb == 0 && seg == 0 && bd == 0) ? 1 : 0)
             | ((cb > 0) ? 2 : 0)
             | ((seg > 0) ? 4 : 0)
             | ((bd != 0) ? 8 : 0)
             | ((fabsf(p2) > 1.0e6f) ? 16 : 0);
    }
    s_cnt[threadIdx.x]  = bad;
    s_bits[threadIdx.x] = bits;
    __syncthreads();
#pragma unroll
    for (int s = NT / 2; s > 0; s >>= 1) {
        if ((int)threadIdx.x < s) {
            s_cnt[threadIdx.x]  += s_cnt[threadIdx.x + s];
            s_bits[threadIdx.x] |= s_bits[threadIdx.x + s];
        }
        __syncthreads();
    }
    if (threadIdx.x == 0 && s_cnt[0] > 0) {
        atomicAdd(&idiag[0], s_cnt[0]);
        atomicOr(&idiag[1], s_bits[0]);
    }
}

// encode idiag -> fdiag: 0 if clean, else 1e5 + bits*1e4 + min(count/100, 9999)
__global__ void encode_kernel(const int* __restrict__ idiag,
                              float* __restrict__ fdiag)
{
    if (threadIdx.x == 0) {
        const int c = idiag[0];
        const int bits = idiag[1];
        float v = 0.0f;
        if (c > 0) {
            int cf = c / 100; if (cf > 9999) cf = 9999;
            v = 100000.0f + (float)bits * 10000.0f + (float)cf;
        }
        fdiag[0] = v;
    }
}

// Pass 2: 131072 slots; min over SEG=4 partials per slot, local sum, block reduce.
__global__ void chamfer_comb_kernel(const float* __restrict__ partial,
                                    float* __restrict__ blockpart)
{
    __shared__ float s_red[NT];
    float sum = 0.0f;
#pragma unroll
    for (int i = 0; i < 4; ++i) {
        const int slot = (int)blockIdx.x * 1024 + i * NT + (int)threadIdx.x;
        const float4 p = ((const float4*)partial)[slot];
        sum += fminf(fminf(p.x, p.y), fminf(p.z, p.w));
    }
    s_red[threadIdx.x] = sum;
    __syncthreads();
#pragma unroll
    for (int s = NT / 2; s > 0; s >>= 1) {
        if ((int)threadIdx.x < s) s_red[threadIdx.x] += s_red[threadIdx.x + s];
        __syncthreads();
    }
    if (threadIdx.x == 0) blockpart[blockIdx.x] = s_red[0];
}

// Pass 3: sum 128 block partials, scale, add diag flag.
__global__ void chamfer_final_kernel(const float* __restrict__ blockpart,
                                     const float* __restrict__ fdiag,
                                     float* __restrict__ out)
{
    __shared__ float s_red[128];
    s_red[threadIdx.x] = blockpart[threadIdx.x];
    __syncthreads();
#pragma unroll
    for (int s = 64; s > 0; s >>= 1) {
        if ((int)threadIdx.x < s) s_red[threadIdx.x] += s_red[threadIdx.x + s];
        __syncthreads();
    }
    if (threadIdx.x == 0)
        out[0] = s_red[0] * (1.0f / (float)(BQ * NPTS)) + fdiag[0];
}

extern "C" void kernel_launch(void* const* d_in, const int* in_sizes, int n_in,
                              void* d_out, int out_size, void* d_ws, size_t ws_size,
                              hipStream_t stream)
{
    const float* preds = (const float*)d_in[0];
    const float* gts   = (const float*)d_in[1];
    float* out       = (float*)d_out;
    float* partial   = (float*)d_ws;                          // 2 MB (SEG=4 layout)
    float* blockpart = partial + (size_t)2 * BQ * NPTS * SEG; // +128 floats
    float* fdiag     = blockpart + 128;                       // +1 float
    int*   idiag     = (int*)(fdiag + 1);                     // +2 ints

    init_diag_kernel<<<1, 64, 0, stream>>>(idiag);

    dim3 grid1(NPTS / BCOLS, SEG, 2 * BQ);   // (8, 4, 32) = 1024 blocks
    chamfer_mfma_kernel<<<grid1, NT, 0, stream>>>(preds, gts, partial);

    dim3 gridv(16, SEG, 2);                  // sampled verify: bd in {0,17}
    verify_kernel<<<gridv, NT, 0, stream>>>(preds, gts, partial, idiag);
    encode_kernel<<<1, 64, 0, stream>>>(idiag, fdiag);

    chamfer_comb_kernel<<<128, NT, 0, stream>>>(partial, blockpart);
    chamfer_final_kernel<<<1, 128, 0, stream>>>(blockpart, fdiag, out);
}

// Round 9
// 34.639 us; speedup vs baseline: 4.1133x; 1.8357x over previous
//
#include <hip/hip_runtime.h>

#define NPTS  4096
#define BQ    16
#define NT    256
#define SEG   4
#define SEGN  (NPTS / SEG)       // 1024 inner points per segment
#define NTILE (SEGN / 16)        // 64 inner tiles (16 points each)
#define WC    8                  // column-tiles (16 cols each) per wave
#define WCOLS (WC * 16)          // 128 cols per wave
#define BCOLS (4 * WCOLS)        // 512 cols per block (4 waves)

typedef short bhalf8  __attribute__((ext_vector_type(8)));   // 8 bf16 (4 VGPRs)
typedef float floatx4 __attribute__((ext_vector_type(4)));   // 16x16 MFMA acc

__device__ __forceinline__ short f2bf(float f) {
    unsigned u = __float_as_uint(f);
    unsigned r = (u + 0x7FFFu + ((u >> 16) & 1u)) >> 16;   // RNE
    return (short)r;
}
__device__ __forceinline__ float bf2f(short s) {
    return __uint_as_float(((unsigned)(unsigned short)s) << 16);
}

// Pass 1 (MFMA): verified R8 structure (pure fminf on MFMA results — no inline
// asm reading MFMA dest regs; that was the R5/R6 RAW-hazard bug).
// Split-bf16 exact product via verified 16x16x32 maps:
// A rows (inner pts, lanes 0-31): k0-7=[ah(3),al(3),xxh,xxl], k8-15=[ah(3),al(3),0,0]
// B cols (outer pts): g0=[yh,yh,1,1], g1=[yl,yl,0,0]  ->  D = xx_i + (-2x_i).y_j
// grid (8, 4, 32) = 1024 blocks, 4/CU.
__global__ __launch_bounds__(NT, 4)
void chamfer_mfma_kernel(const float* __restrict__ preds,
                         const float* __restrict__ gts,
                         float* __restrict__ partial)
{
    __shared__ bhalf8 s_frag[NTILE * 32];   // 32 KB

    const int cb  = blockIdx.x;   // 0..7
    const int seg = blockIdx.y;   // 0..3
    const int bd  = blockIdx.z;   // 0..31
    const int dir = bd >> 4;
    const int b   = bd & 15;

    const float* outer = (dir == 0) ? preds : gts;
    const float* inner = (dir == 0) ? gts   : preds;
    const float* ob = outer + (size_t)b * NPTS * 3;
    const float* ib = inner + (size_t)b * NPTS * 3 + (size_t)seg * SEGN * 3;

    // ---- stage A fragments (inner points) ----
    for (int p = (int)threadIdx.x; p < SEGN; p += NT) {
        const float x0 = ib[p * 3 + 0], x1 = ib[p * 3 + 1], x2 = ib[p * 3 + 2];
        const float a0 = -2.0f * x0, a1 = -2.0f * x1, a2 = -2.0f * x2;
        const short h0 = f2bf(a0), h1 = f2bf(a1), h2 = f2bf(a2);
        const short l0 = f2bf(a0 - bf2f(h0));
        const short l1 = f2bf(a1 - bf2f(h1));
        const short l2 = f2bf(a2 - bf2f(h2));
        const float xx = x0 * x0 + x1 * x1 + x2 * x2;
        const short xh = f2bf(xx);
        const short xl = f2bf(xx - bf2f(xh));
        bhalf8 e0, e1;
        e0[0] = h0; e0[1] = h1; e0[2] = h2; e0[3] = l0;
        e0[4] = l1; e0[5] = l2; e0[6] = xh; e0[7] = xl;
        e1[0] = h0; e1[1] = h1; e1[2] = h2; e1[3] = l0;
        e1[4] = l1; e1[5] = l2; e1[6] = 0;  e1[7] = 0;
        const int t = p >> 4, r = p & 15;
        s_frag[t * 32 + r]      = e0;   // k-group 0 rows (lanes 0-15)
        s_frag[t * 32 + 16 + r] = e1;   // k-group 1 rows (lanes 16-31)
    }

    const int wv   = (int)threadIdx.x >> 6;
    const int lane = (int)threadIdx.x & 63;
    const int g    = lane >> 4;
    const int colbase = cb * BCOLS + wv * WCOLS;

    const bhalf8 z8 = {0, 0, 0, 0, 0, 0, 0, 0};

    bhalf8 bfrag[WC];
    float  yy[WC];
#pragma unroll
    for (int ct = 0; ct < WC; ++ct) {
        const int col = colbase + ct * 16 + (lane & 15);
        const float y0 = ob[col * 3 + 0], y1 = ob[col * 3 + 1], y2 = ob[col * 3 + 2];
        yy[ct] = y0 * y0 + y1 * y1 + y2 * y2;
        bhalf8 f = z8;
        if (g == 0) {          // k 0-7: [yhi(3), yhi(3), 1, 1]
            const short h0 = f2bf(y0), h1 = f2bf(y1), h2 = f2bf(y2);
            f[0] = h0; f[1] = h1; f[2] = h2; f[3] = h0; f[4] = h1; f[5] = h2;
            f[6] = (short)0x3F80; f[7] = (short)0x3F80;   // bf16 1.0
        } else if (g == 1) {   // k 8-15: [ylo(3), ylo(3), 0, 0]
            const short h0 = f2bf(y0), h1 = f2bf(y1), h2 = f2bf(y2);
            const short q0 = f2bf(y0 - bf2f(h0));
            const short q1 = f2bf(y1 - bf2f(h1));
            const short q2 = f2bf(y2 - bf2f(h2));
            f[0] = q0; f[1] = q1; f[2] = q2; f[3] = q0; f[4] = q1; f[5] = q2;
        }
        bfrag[ct] = f;
    }
    __syncthreads();

    float accm[WC];
#pragma unroll
    for (int ct = 0; ct < WC; ++ct) accm[ct] = 3.0e38f;

    const floatx4 zacc = {0.0f, 0.0f, 0.0f, 0.0f};

#pragma unroll 2
    for (int t = 0; t < NTILE; ++t) {
        bhalf8 a = z8;
        if (lane < 32) a = s_frag[t * 32 + lane];
#pragma unroll
        for (int ct = 0; ct < WC; ++ct) {
            const floatx4 c = __builtin_amdgcn_mfma_f32_16x16x32_bf16(a, bfrag[ct], zacc, 0, 0, 0);
            accm[ct] = fminf(fminf(fminf(fminf(c[0], c[1]), c[2]), c[3]), accm[ct]);
        }
    }

#pragma unroll
    for (int ct = 0; ct < WC; ++ct) {
        float v = accm[ct];
        v = fminf(v, __shfl_xor(v, 16, 64));
        v = fminf(v, __shfl_xor(v, 32, 64));
        const float m = v + yy[ct];
        if (lane < 16) {
            const int col = colbase + ct * 16 + lane;
            partial[((size_t)bd * NPTS + col) * SEG + seg] = m;
        }
    }
}

// Pass 2: 131072 slots; min over SEG=4 partials per slot, local sum, block reduce.
__global__ void chamfer_comb_kernel(const float* __restrict__ partial,
                                    float* __restrict__ blockpart)
{
    __shared__ float s_red[NT];
    float sum = 0.0f;
#pragma unroll
    for (int i = 0; i < 4; ++i) {
        const int slot = (int)blockIdx.x * 1024 + i * NT + (int)threadIdx.x;
        const float4 p = ((const float4*)partial)[slot];
        sum += fminf(fminf(p.x, p.y), fminf(p.z, p.w));
    }
    s_red[threadIdx.x] = sum;
    __syncthreads();
#pragma unroll
    for (int s = NT / 2; s > 0; s >>= 1) {
        if ((int)threadIdx.x < s) s_red[threadIdx.x] += s_red[threadIdx.x + s];
        __syncthreads();
    }
    if (threadIdx.x == 0) blockpart[blockIdx.x] = s_red[0];
}

// Pass 3: sum 128 block partials, scale by 1/(B*N).
__global__ void chamfer_final_kernel(const float* __restrict__ blockpart,
                                     float* __restrict__ out)
{
    __shared__ float s_red[128];
    s_red[threadIdx.x] = blockpart[threadIdx.x];
    __syncthreads();
#pragma unroll
    for (int s = 64; s > 0; s >>= 1) {
        if ((int)threadIdx.x < s) s_red[threadIdx.x] += s_red[threadIdx.x + s];
        __syncthreads();
    }
    if (threadIdx.x == 0) out[0] = s_red[0] * (1.0f / (float)(BQ * NPTS));
}

extern "C" void kernel_launch(void* const* d_in, const int* in_sizes, int n_in,
                              void* d_out, int out_size, void* d_ws, size_t ws_size,
                              hipStream_t stream)
{
    const float* preds = (const float*)d_in[0];
    const float* gts   = (const float*)d_in[1];
    float* out       = (float*)d_out;
    float* partial   = (float*)d_ws;                          // 2 MB
    float* blockpart = partial + (size_t)2 * BQ * NPTS * SEG; // +128 floats

    dim3 grid1(NPTS / BCOLS, SEG, 2 * BQ);   // (8, 4, 32) = 1024 blocks
    chamfer_mfma_kernel<<<grid1, NT, 0, stream>>>(preds, gts, partial);
    chamfer_comb_kernel<<<128, NT, 0, stream>>>(partial, blockpart);
    chamfer_final_kernel<<<1, 128, 0, stream>>>(blockpart, out);
}

// Round 10
// 28.472 us; speedup vs baseline: 5.0043x; 1.2166x over previous
//
#include <hip/hip_runtime.h>

#define NPTS  4096
#define BQ    16
#define NT    256
#define SEG   4
#define SEGN  (NPTS / SEG)       // 1024 inner points per segment
#define NT32  (SEGN / 32)        // 32 inner tiles (32 points each)
#define WC    4                  // column-tiles (32 cols each) per wave
#define WCOLS (WC * 32)          // 128 cols per wave
#define BCOLS (4 * WCOLS)        // 512 cols per block (4 waves)

typedef short bhalf8   __attribute__((ext_vector_type(8)));   // 8 bf16 (4 VGPRs)
typedef float floatx16 __attribute__((ext_vector_type(16)));  // 32x32 MFMA acc

__device__ __forceinline__ short f2bf(float f) {
    unsigned u = __float_as_uint(f);
    unsigned r = (u + 0x7FFFu + ((u >> 16) & 1u)) >> 16;   // RNE
    return (short)r;
}
__device__ __forceinline__ float bf2f(short s) {
    return __uint_as_float(((unsigned)(unsigned short)s) << 16);
}

// Pass 1 (MFMA 32x32x16): one MFMA = 32 inner pts x 32 outer cols, D = FULL
// squared distance (xx and yy both folded in via split-bf16 slots):
//   A row i: g0=[ah(3),al(3),xxh,xxl], g1=[ah(3),al(3),1,1]   (a=-2x)
//   B col j: g0=[yh(3),yh(3),1,1],     g1=[yl(3),yl(3),yyh,yyl]
//   => D[i][j] = (ah+al).(yh+yl) + xx + yy   (repr error only)
// Epilogue: pure fminf tree over 16 regs + shfl_xor(32) -> col min over all
// 32 rows (robust to any row permutation; C/D col=lane&31 verified m74/m101).
// NO inline asm reads MFMA results (R5/R6 RAW-hazard lesson).
// grid (8, 4, 32) = 1024 blocks, 4/CU.
__global__ __launch_bounds__(NT, 4)
void chamfer_mfma_kernel(const float* __restrict__ preds,
                         const float* __restrict__ gts,
                         float* __restrict__ partial)
{
    __shared__ bhalf8 s_frag[NT32 * 64];   // 32 KB

    const int cb  = blockIdx.x;   // 0..7
    const int seg = blockIdx.y;   // 0..3
    const int bd  = blockIdx.z;   // 0..31
    const int dir = bd >> 4;
    const int b   = bd & 15;

    const float* outer = (dir == 0) ? preds : gts;
    const float* inner = (dir == 0) ? gts   : preds;
    const float* ob = outer + (size_t)b * NPTS * 3;
    const float* ib = inner + (size_t)b * NPTS * 3 + (size_t)seg * SEGN * 3;

    const short one = (short)0x3F80;   // bf16 1.0

    // ---- stage A fragments (inner points) ----
    for (int p = (int)threadIdx.x; p < SEGN; p += NT) {
        const float x0 = ib[p * 3 + 0], x1 = ib[p * 3 + 1], x2 = ib[p * 3 + 2];
        const float a0 = -2.0f * x0, a1 = -2.0f * x1, a2 = -2.0f * x2;
        const short h0 = f2bf(a0), h1 = f2bf(a1), h2 = f2bf(a2);
        const short l0 = f2bf(a0 - bf2f(h0));
        const short l1 = f2bf(a1 - bf2f(h1));
        const short l2 = f2bf(a2 - bf2f(h2));
        const float xx = x0 * x0 + x1 * x1 + x2 * x2;
        const short xh = f2bf(xx);
        const short xl = f2bf(xx - bf2f(xh));
        bhalf8 e0, e1;
        e0[0] = h0; e0[1] = h1; e0[2] = h2; e0[3] = l0;
        e0[4] = l1; e0[5] = l2; e0[6] = xh;  e0[7] = xl;
        e1[0] = h0; e1[1] = h1; e1[2] = h2; e1[3] = l0;
        e1[4] = l1; e1[5] = l2; e1[6] = one; e1[7] = one;
        const int t = p >> 5, r = p & 31;
        s_frag[t * 64 + r]      = e0;   // k-group 0 rows (lanes 0-31)
        s_frag[t * 64 + 32 + r] = e1;   // k-group 1 rows (lanes 32-63)
    }

    const int wv   = (int)threadIdx.x >> 6;
    const int lane = (int)threadIdx.x & 63;
    const int g    = lane >> 5;          // k-group 0..1
    const int colbase = cb * BCOLS + wv * WCOLS;

    bhalf8 bfrag[WC];
#pragma unroll
    for (int ct = 0; ct < WC; ++ct) {
        const int col = colbase + ct * 32 + (lane & 31);
        const float y0 = ob[col * 3 + 0], y1 = ob[col * 3 + 1], y2 = ob[col * 3 + 2];
        const short h0 = f2bf(y0), h1 = f2bf(y1), h2 = f2bf(y2);
        bhalf8 f;
        if (g == 0) {          // k 0-7: [yh(3), yh(3), 1, 1]
            f[0] = h0; f[1] = h1; f[2] = h2; f[3] = h0; f[4] = h1; f[5] = h2;
            f[6] = one; f[7] = one;
        } else {               // k 8-15: [yl(3), yl(3), yyh, yyl]
            const short q0 = f2bf(y0 - bf2f(h0));
            const short q1 = f2bf(y1 - bf2f(h1));
            const short q2 = f2bf(y2 - bf2f(h2));
            const float yy = y0 * y0 + y1 * y1 + y2 * y2;
            const short yh = f2bf(yy);
            const short yl = f2bf(yy - bf2f(yh));
            f[0] = q0; f[1] = q1; f[2] = q2; f[3] = q0; f[4] = q1; f[5] = q2;
            f[6] = yh; f[7] = yl;
        }
        bfrag[ct] = f;
    }
    __syncthreads();

    float accm[WC];
#pragma unroll
    for (int ct = 0; ct < WC; ++ct) accm[ct] = 3.0e38f;

    const floatx16 zacc = {0,0,0,0,0,0,0,0,0,0,0,0,0,0,0,0};

#pragma unroll 2
    for (int t = 0; t < NT32; ++t) {
        const bhalf8 a = s_frag[t * 64 + lane];
#pragma unroll
        for (int ct = 0; ct < WC; ++ct) {
            const floatx16 c = __builtin_amdgcn_mfma_f32_32x32x16_bf16(a, bfrag[ct], zacc, 0, 0, 0);
            // nested fminf triples -> v_min3_f32 fusion; 16 regs + acc
            const float m0 = fminf(fminf(c[0],  c[1]),  c[2]);
            const float m1 = fminf(fminf(c[3],  c[4]),  c[5]);
            const float m2 = fminf(fminf(c[6],  c[7]),  c[8]);
            const float m3 = fminf(fminf(c[9],  c[10]), c[11]);
            const float m4 = fminf(fminf(c[12], c[13]), c[14]);
            const float m5 = fminf(fminf(m0, m1), m2);
            const float m6 = fminf(fminf(m3, m4), c[15]);
            accm[ct] = fminf(fminf(m5, m6), accm[ct]);
        }
    }

    // full col-min: this lane's 16 rows + the other lane-half's 16 rows
#pragma unroll
    for (int ct = 0; ct < WC; ++ct) {
        float v = accm[ct];
        v = fminf(v, __shfl_xor(v, 32, 64));
        if (lane < 32) {
            const int col = colbase + ct * 32 + lane;
            partial[((size_t)bd * NPTS + col) * SEG + seg] = v;
        }
    }
}

// Pass 2: 131072 slots; min over SEG=4 partials per slot, local sum, block reduce.
__global__ void chamfer_comb_kernel(const float* __restrict__ partial,
                                    float* __restrict__ blockpart)
{
    __shared__ float s_red[NT];
    float sum = 0.0f;
#pragma unroll
    for (int i = 0; i < 4; ++i) {
        const int slot = (int)blockIdx.x * 1024 + i * NT + (int)threadIdx.x;
        const float4 p = ((const float4*)partial)[slot];
        sum += fminf(fminf(p.x, p.y), fminf(p.z, p.w));
    }
    s_red[threadIdx.x] = sum;
    __syncthreads();
#pragma unroll
    for (int s = NT / 2; s > 0; s >>= 1) {
        if ((int)threadIdx.x < s) s_red[threadIdx.x] += s_red[threadIdx.x + s];
        __syncthreads();
    }
    if (threadIdx.x == 0) blockpart[blockIdx.x] = s_red[0];
}

// Pass 3: sum 128 block partials, scale by 1/(B*N).
__global__ void chamfer_final_kernel(const float* __restrict__ blockpart,
                                     float* __restrict__ out)
{
    __shared__ float s_red[128];
    s_red[threadIdx.x] = blockpart[threadIdx.x];
    __syncthreads();
#pragma unroll
    for (int s = 64; s > 0; s >>= 1) {
        if ((int)threadIdx.x < s) s_red[threadIdx.x] += s_red[threadIdx.x + s];
        __syncthreads();
    }
    if (threadIdx.x == 0) out[0] = s_red[0] * (1.0f / (float)(BQ * NPTS));
}

extern "C" void kernel_launch(void* const* d_in, const int* in_sizes, int n_in,
                              void* d_out, int out_size, void* d_ws, size_t ws_size,
                              hipStream_t stream)
{
    const float* preds = (const float*)d_in[0];
    const float* gts   = (const float*)d_in[1];
    float* out       = (float*)d_out;
    float* partial   = (float*)d_ws;                          // 2 MB
    float* blockpart = partial + (size_t)2 * BQ * NPTS * SEG; // +128 floats

    dim3 grid1(NPTS / BCOLS, SEG, 2 * BQ);   // (8, 4, 32) = 1024 blocks
    chamfer_mfma_kernel<<<grid1, NT, 0, stream>>>(preds, gts, partial);
    chamfer_comb_kernel<<<128, NT, 0, stream>>>(partial, blockpart);
    chamfer_final_kernel<<<1, 128, 0, stream>>>(blockpart, out);
}